// Round 1
// baseline (592.466 us; speedup 1.0000x reference)
//
#include <hip/hip_runtime.h>

typedef float  f32x4  __attribute__((ext_vector_type(4)));
typedef __bf16 bf16x8 __attribute__((ext_vector_type(8)));
typedef __bf16 bf16x4 __attribute__((ext_vector_type(4)));

#define DEVFN static __device__ __forceinline__

constexpr int BB = 2, SS = 4096, DD = 1024;
constexpr int MROWS = BB * SS; // 8192

// ---------------- workspace layout (bytes) ----------------
constexpr size_t SZ_QK   = (size_t)MROWS * DD * 2;   // 16 MiB  (bf16 [8192][1024])
constexpr size_t SZ_VT   = (size_t)BB * DD * SS * 2; // 16 MiB  (bf16 [2][1024][4096])
constexpr size_t SZ_ATTN = (size_t)BB * SS * SS * 2; // 64 MiB  (bf16 [2][4096][4096])
constexpr size_t SZ_S    = (size_t)BB * SS * SS * 4; // 128 MiB (f32  [2][4096][4096])
constexpr size_t SZ_W    = (size_t)DD * DD * 2;      // 2 MiB

constexpr size_t O_VT   = 0;
constexpr size_t O_ATTN = O_VT + SZ_VT;
constexpr size_t O_QH   = O_ATTN;            // Q/K hi/lo splits live here until softmax
constexpr size_t O_QL   = O_QH + SZ_QK;      // overwrites them with attn bf16
constexpr size_t O_KH   = O_QL + SZ_QK;
constexpr size_t O_KL   = O_KH + SZ_QK;
constexpr size_t O_S    = O_ATTN + SZ_ATTN;
// phase-1 aliases inside the scores region (dead before scores GEMM writes)
constexpr size_t O_XH   = O_S;
constexpr size_t O_XL   = O_XH + SZ_QK;
constexpr size_t O_WQH  = O_XL + SZ_QK;
constexpr size_t O_WQL  = O_WQH + SZ_W;
constexpr size_t O_WKH  = O_WQL + SZ_W;
constexpr size_t O_WKL  = O_WKH + SZ_W;
constexpr size_t O_WVH  = O_WKL + SZ_W;
constexpr size_t O_WVL  = O_WVH + SZ_W;
constexpr size_t O_V    = O_WVL + SZ_W;
constexpr size_t WS_NEEDED = SZ_VT + SZ_ATTN + SZ_S; // ~218 MB

// ---------------- helpers ----------------
DEVFN f32x4 mfma16x16x32(bf16x8 a, bf16x8 b, f32x4 c) {
  return __builtin_amdgcn_mfma_f32_16x16x32_bf16(a, b, c, 0, 0, 0);
}

// Stage one [128][32] bf16 tile, row-major, via global_load_lds (16B/lane).
// gptr must already point at &src[(row0 + tid/4)*ld + k0 + (tid&3)*8].
DEVFN void stage_tile(__bf16* ldsb, const __bf16* gptr, int ld, int tid) {
  char* lb = (char*)ldsb + ((tid >> 6) << 10); // wave-uniform base; HW adds lane*16
  __builtin_amdgcn_global_load_lds((const __attribute__((address_space(1))) void*)gptr,
                                   (__attribute__((address_space(3))) void*)lb, 16, 0, 0);
  __builtin_amdgcn_global_load_lds((const __attribute__((address_space(1))) void*)(gptr + (size_t)64 * ld),
                                   (__attribute__((address_space(3))) void*)(lb + 4096), 16, 0, 0);
}

// ---------------- split fp32 -> bf16 hi/lo ----------------
__global__ __launch_bounds__(256)
void split_f32_bf16x2(const float* __restrict__ in, __bf16* __restrict__ hi,
                      __bf16* __restrict__ lo, int n) {
  int stride = gridDim.x * blockDim.x;
  for (int i = blockIdx.x * blockDim.x + threadIdx.x; i * 4 < n; i += stride) {
    f32x4 x = *(const f32x4*)(in + (size_t)i * 4);
    bf16x4 h, l;
#pragma unroll
    for (int e = 0; e < 4; ++e) {
      __bf16 hh = (__bf16)x[e];
      h[e] = hh;
      l[e] = (__bf16)(x[e] - (float)hh);
    }
    *(bf16x4*)(hi + (size_t)i * 4) = h;
    *(bf16x4*)(lo + (size_t)i * 4) = l;
  }
}

// ---------------- GEMM, B^T layout (A [M][K], B [N][K], both K-contiguous) -------------
// NPASS: 1 = plain bf16 (Ah*Bh), 3 = split (AhBh + AhBl + AlBh)
// EPI:   0 = write fp32 (no bias), 1 = write split hi/lo bf16 (+bias), 2 = write bf16 (+bias)
template<int NPASS, int EPI>
__global__ __launch_bounds__(256)
void gemm_bt(const __bf16* __restrict__ Ah, const __bf16* __restrict__ Al,
             const __bf16* __restrict__ Bh, const __bf16* __restrict__ Bl,
             const float* __restrict__ bias,
             float* __restrict__ Cf, __bf16* __restrict__ Ch, __bf16* __restrict__ Cl,
             int M, int N, int K,
             size_t sAb, size_t sBb, size_t sCb) {
  const int b = blockIdx.z;
  Ah += (size_t)b * sAb; Bh += (size_t)b * sBb;
  if (NPASS == 3) { Al += (size_t)b * sAb; Bl += (size_t)b * sBb; }

  __shared__ __bf16 lds[(NPASS == 3) ? 4 : 2][128 * 32]; // [0]=Ah [1]=Bh [2]=Al [3]=Bl

  const int tid  = threadIdx.x;
  const int lane = tid & 63, wave = tid >> 6;
  const int wm = (wave >> 1) * 64, wn = (wave & 1) * 64;
  const int row0 = blockIdx.y * 128, col0 = blockIdx.x * 128;
  const int sr = tid >> 2, sc = (tid & 3) * 8;

  const __bf16* gA  = Ah + (size_t)(row0 + sr) * K + sc;
  const __bf16* gB  = Bh + (size_t)(col0 + sr) * K + sc;
  const __bf16* gAl = (NPASS == 3) ? (Al + (size_t)(row0 + sr) * K + sc) : nullptr;
  const __bf16* gBl = (NPASS == 3) ? (Bl + (size_t)(col0 + sr) * K + sc) : nullptr;

  f32x4 acc[4][4] = {};

  for (int k0 = 0; k0 < K; k0 += 32) {
    __syncthreads();
    stage_tile(lds[0], gA + k0, K, tid);
    stage_tile(lds[1], gB + k0, K, tid);
    if (NPASS == 3) {
      stage_tile(lds[2], gAl + k0, K, tid);
      stage_tile(lds[3], gBl + k0, K, tid);
    }
    __syncthreads();

    const int kg = (lane >> 4) * 8;
    bf16x8 ah[4], bh[4], al[4], bl[4];
#pragma unroll
    for (int m = 0; m < 4; ++m) {
      int r = wm + m * 16 + (lane & 15);
      ah[m] = *(const bf16x8*)&lds[0][r * 32 + kg];
      if (NPASS == 3) al[m] = *(const bf16x8*)&lds[2][r * 32 + kg];
    }
#pragma unroll
    for (int n = 0; n < 4; ++n) {
      int r = wn + n * 16 + (lane & 15);
      bh[n] = *(const bf16x8*)&lds[1][r * 32 + kg];
      if (NPASS == 3) bl[n] = *(const bf16x8*)&lds[3][r * 32 + kg];
    }
#pragma unroll
    for (int m = 0; m < 4; ++m)
#pragma unroll
      for (int n = 0; n < 4; ++n) {
        acc[m][n] = mfma16x16x32(ah[m], bh[n], acc[m][n]);
        if (NPASS == 3) {
          acc[m][n] = mfma16x16x32(ah[m], bl[n], acc[m][n]);
          acc[m][n] = mfma16x16x32(al[m], bh[n], acc[m][n]);
        }
      }
  }

  if (EPI == 0) { Cf += (size_t)b * sCb; }
  else { Ch += (size_t)b * sCb; if (EPI == 1) Cl += (size_t)b * sCb; }

#pragma unroll
  for (int m = 0; m < 4; ++m)
#pragma unroll
    for (int n = 0; n < 4; ++n) {
      int gcol = col0 + wn + n * 16 + (lane & 15);
      float bvv = (EPI != 0) ? bias[gcol] : 0.0f;
      f32x4 f = acc[m][n];
#pragma unroll
      for (int j = 0; j < 4; ++j) {
        int grow = row0 + wm + m * 16 + (lane >> 4) * 4 + j;
        float v = f[j] + bvv;
        size_t idx = (size_t)grow * N + gcol;
        if (EPI == 0) {
          Cf[idx] = v;
        } else if (EPI == 1) {
          __bf16 h = (__bf16)v;
          Ch[idx] = h;
          Cl[idx] = (__bf16)(v - (float)h);
        } else {
          Ch[idx] = (__bf16)v;
        }
      }
    }
}

// ---------------- transpose bf16 [rows][cols] -> [cols][rows], per batch -------------
__global__ __launch_bounds__(256)
void transpose_bf16(const __bf16* __restrict__ in, __bf16* __restrict__ out,
                    int rows, int cols) {
  __shared__ __bf16 t[32][33];
  const int b = blockIdx.z;
  in  += (size_t)b * rows * cols;
  out += (size_t)b * rows * cols;
  const int i0 = blockIdx.y * 32, j0 = blockIdx.x * 32;
  const int tx = threadIdx.x & 31, ty0 = threadIdx.x >> 5;
#pragma unroll
  for (int p = 0; p < 4; ++p) {
    int ty = ty0 + p * 8;
    t[ty][tx] = in[(size_t)(i0 + ty) * cols + (j0 + tx)];
  }
  __syncthreads();
#pragma unroll
  for (int p = 0; p < 4; ++p) {
    int ty = ty0 + p * 8;
    out[(size_t)(j0 + ty) * rows + (i0 + tx)] = t[tx][ty];
  }
}

// ---------------- softmax + dropout: f32 scores row -> bf16 attn row -------------
__global__ __launch_bounds__(256)
void softmax_dropout(const float* __restrict__ Sf, const float* __restrict__ U,
                     __bf16* __restrict__ P) {
  __shared__ float red[4];
  const size_t row = blockIdx.x;
  const float* s = Sf + row * SS;
  const float* u = U + row * SS;
  __bf16* p = P + row * SS;
  const int tid = threadIdx.x, lane = tid & 63, wave = tid >> 6;

  f32x4 v[4];
  float m = -3.0e38f;
#pragma unroll
  for (int j = 0; j < 4; ++j) {
    v[j] = *(const f32x4*)(s + (size_t)(j * 256 + tid) * 4);
#pragma unroll
    for (int e = 0; e < 4; ++e) m = fmaxf(m, v[j][e]);
  }
#pragma unroll
  for (int o = 32; o > 0; o >>= 1) m = fmaxf(m, __shfl_xor(m, o));
  if (lane == 0) red[wave] = m;
  __syncthreads();
  m = fmaxf(fmaxf(red[0], red[1]), fmaxf(red[2], red[3]));

  float sum = 0.0f;
#pragma unroll
  for (int j = 0; j < 4; ++j)
#pragma unroll
    for (int e = 0; e < 4; ++e) { float ex = __expf(v[j][e] - m); v[j][e] = ex; sum += ex; }
#pragma unroll
  for (int o = 32; o > 0; o >>= 1) sum += __shfl_xor(sum, o);
  __syncthreads(); // protect red[] reuse
  if (lane == 0) red[wave] = sum;
  __syncthreads();
  sum = red[0] + red[1] + red[2] + red[3];
  const float scale = 1.25f / sum; // includes 1/(1-p)

#pragma unroll
  for (int j = 0; j < 4; ++j) {
    f32x4 uu = *(const f32x4*)(u + (size_t)(j * 256 + tid) * 4);
    bf16x4 out;
#pragma unroll
    for (int e = 0; e < 4; ++e)
      out[e] = (__bf16)((uu[e] >= 0.2f) ? v[j][e] * scale : 0.0f);
    *(bf16x4*)(p + (size_t)(j * 256 + tid) * 4) = out;
  }
}

// ---------------- launcher ----------------
extern "C" void kernel_launch(void* const* d_in, const int* in_sizes, int n_in,
                              void* d_out, int out_size, void* d_ws, size_t ws_size,
                              hipStream_t stream) {
  if (ws_size < WS_NEEDED) return; // diagnostic: output stays zero -> absmax == max|ref|

  const float* x  = (const float*)d_in[0];
  const float* Wq = (const float*)d_in[1];
  const float* bq = (const float*)d_in[2];
  const float* Wk = (const float*)d_in[3];
  const float* bk = (const float*)d_in[4];
  const float* Wv = (const float*)d_in[5];
  const float* bv = (const float*)d_in[6];
  const float* du = (const float*)d_in[7];

  char* ws = (char*)d_ws;
  __bf16* Vt  = (__bf16*)(ws + O_VT);
  __bf16* Pb  = (__bf16*)(ws + O_ATTN);
  __bf16* Qh  = (__bf16*)(ws + O_QH);
  __bf16* Ql  = (__bf16*)(ws + O_QL);
  __bf16* Kh  = (__bf16*)(ws + O_KH);
  __bf16* Kl  = (__bf16*)(ws + O_KL);
  float*  Sf  = (float*) (ws + O_S);
  __bf16* xh  = (__bf16*)(ws + O_XH);
  __bf16* xl  = (__bf16*)(ws + O_XL);
  __bf16* wqh = (__bf16*)(ws + O_WQH);
  __bf16* wql = (__bf16*)(ws + O_WQL);
  __bf16* wkh = (__bf16*)(ws + O_WKH);
  __bf16* wkl = (__bf16*)(ws + O_WKL);
  __bf16* wvh = (__bf16*)(ws + O_WVH);
  __bf16* wvl = (__bf16*)(ws + O_WVL);
  __bf16* Vb  = (__bf16*)(ws + O_V);
  float*  out = (float*)d_out;

  // 1) splits
  split_f32_bf16x2<<<2048, 256, 0, stream>>>(x,  xh,  xl,  MROWS * DD);
  split_f32_bf16x2<<<256,  256, 0, stream>>>(Wq, wqh, wql, DD * DD);
  split_f32_bf16x2<<<256,  256, 0, stream>>>(Wk, wkh, wkl, DD * DD);
  split_f32_bf16x2<<<256,  256, 0, stream>>>(Wv, wvh, wvl, DD * DD);

  // 2) projections (M=8192, N=1024, K=1024; W is [N][K] = B^T layout)
  dim3 gp(DD / 128, MROWS / 128, 1);
  gemm_bt<3, 1><<<gp, 256, 0, stream>>>(xh, xl, wqh, wql, bq, nullptr, Qh, Ql,
                                        MROWS, DD, DD, 0, 0, 0);
  gemm_bt<3, 1><<<gp, 256, 0, stream>>>(xh, xl, wkh, wkl, bk, nullptr, Kh, Kl,
                                        MROWS, DD, DD, 0, 0, 0);
  gemm_bt<3, 2><<<gp, 256, 0, stream>>>(xh, xl, wvh, wvl, bv, nullptr, Vb, nullptr,
                                        MROWS, DD, DD, 0, 0, 0);

  // 3) V transpose -> Vt [2][1024][4096]
  transpose_bf16<<<dim3(DD / 32, SS / 32, BB), 256, 0, stream>>>(Vb, Vt, SS, DD);

  // 4) scores = Q K^T (split, fp32 out)  M=N=4096, K=1024, 2 batches
  gemm_bt<3, 0><<<dim3(SS / 128, SS / 128, BB), 256, 0, stream>>>(
      Qh, Ql, Kh, Kl, nullptr, Sf, nullptr, nullptr,
      SS, SS, DD, (size_t)SS * DD, (size_t)SS * DD, (size_t)SS * SS);

  // 5) softmax + dropout -> attn bf16 (overwrites dead Q/K splits)
  softmax_dropout<<<MROWS, 256, 0, stream>>>(Sf, du, Pb);

  // 6) out = attn @ V  (A = attn [4096][4096], B = Vt [1024][4096]) -> d_out fp32
  gemm_bt<1, 0><<<dim3(DD / 128, SS / 128, BB), 256, 0, stream>>>(
      Pb, nullptr, Vt, nullptr, nullptr, out, nullptr, nullptr,
      SS, DD, SS, (size_t)SS * SS, (size_t)DD * SS, (size_t)SS * DD);
}

// Round 2
// 519.308 us; speedup vs baseline: 1.1409x; 1.1409x over previous
//
#include <hip/hip_runtime.h>

typedef float  f32x4  __attribute__((ext_vector_type(4)));
typedef __bf16 bf16x8 __attribute__((ext_vector_type(8)));
typedef __bf16 bf16x4 __attribute__((ext_vector_type(4)));

#define DEVFN static __device__ __forceinline__

constexpr int BB = 2, SS = 4096, DD = 1024;
constexpr int MROWS = BB * SS; // 8192

// ---------------- workspace layout (bytes) ----------------
constexpr size_t SZ_QK   = (size_t)MROWS * DD * 2;
constexpr size_t SZ_VT   = (size_t)BB * DD * SS * 2;
constexpr size_t SZ_ATTN = (size_t)BB * SS * SS * 2;
constexpr size_t SZ_S    = (size_t)BB * SS * SS * 4;
constexpr size_t SZ_W    = (size_t)DD * DD * 2;

constexpr size_t O_VT   = 0;
constexpr size_t O_ATTN = O_VT + SZ_VT;
constexpr size_t O_QH   = O_ATTN;
constexpr size_t O_QL   = O_QH + SZ_QK;
constexpr size_t O_KH   = O_QL + SZ_QK;
constexpr size_t O_KL   = O_KH + SZ_QK;
constexpr size_t O_S    = O_ATTN + SZ_ATTN;
constexpr size_t O_XH   = O_S;
constexpr size_t O_XL   = O_XH + SZ_QK;
constexpr size_t O_WQH  = O_XL + SZ_QK;
constexpr size_t O_WQL  = O_WQH + SZ_W;
constexpr size_t O_WKH  = O_WQL + SZ_W;
constexpr size_t O_WKL  = O_WKH + SZ_W;
constexpr size_t O_WVH  = O_WKL + SZ_W;
constexpr size_t O_WVL  = O_WVH + SZ_W;
constexpr size_t O_V    = O_WVL + SZ_W;
constexpr size_t WS_NEEDED = SZ_VT + SZ_ATTN + SZ_S;

// ---------------- helpers ----------------
DEVFN f32x4 mfma16x16x32(bf16x8 a, bf16x8 b, f32x4 c) {
  return __builtin_amdgcn_mfma_f32_16x16x32_bf16(a, b, c, 0, 0, 0);
}

DEVFN void gld16(const __bf16* g, char* l) {
  __builtin_amdgcn_global_load_lds((const __attribute__((address_space(1))) void*)g,
                                   (__attribute__((address_space(3))) void*)l, 16, 0, 0);
}

// =====================================================================
// 256x256 8-phase GEMM core (B^T layout, K-concatenated 3-segment split).
// A sources: s.a[seg] row-major [M][1024]; B sources: s.b[seg] [N][1024].
// K' = NT*64; seg = tile>>4 (each 1024-K segment = 16 tiles of 64).
// LDS: 128 KiB dynamic: Abuf0(32K) Bbuf0(32K) Abuf1(32K) Bbuf1(32K).
// Swizzle: lds_byte(row,kElem) = (row*128 + kElem*2) ^ ((row&7)<<4).
// Staged linearly by global_load_lds with inverse-swizzled global source.
// =====================================================================
struct Segs { const __bf16 *a0, *a1, *a2, *b0, *b1, *b2; };

DEVFN void gemm256_core(Segs s, int NT, char* smem, f32x4 (&acc)[8][4]) {
  const int tid = threadIdx.x, lane = tid & 63, wave = tid >> 6;
  const int wm = wave >> 2, wn = wave & 3;
  // staging: per-lane inverse-swizzled source offset (row-in-quarter * ld + k-xor)
  const size_t rk = (size_t)((wave << 3) + (lane >> 3)) * DD +
                    (size_t)((((lane & 7) ^ (lane >> 3)) << 3));
  const int wvoff = wave << 10; // wave-uniform LDS byte base within quarter
  // fragment-read addressing (swizzled)
  const int rbA = (((wm << 7) + (lane & 15)) << 7);
  const int rbB = (((wn << 6) + (lane & 15)) << 7);
  const int cx0 = ((((lane >> 4) << 4)) ^ ((lane & 7) << 4));
  const int cx1 = cx0 ^ 64;

  char* LA0 = smem;
  char* LB0 = smem + 32768;
  char* LA1 = smem + 65536;
  char* LB1 = smem + 98304;

  auto stA = [&](int u, int q, char* dst) {
    int uc = (u < NT) ? u : (NT - 1); // tail clamp keeps vmcnt counts uniform
    int sg = uc >> 4;
    const __bf16* p = (sg == 0) ? s.a0 : ((sg == 1) ? s.a1 : s.a2);
    gld16(p + ((size_t)(q << 6)) * DD + ((uc & 15) << 6) + rk, dst + (q << 13) + wvoff);
  };
  auto stB = [&](int u, int q, char* dst) {
    int uc = (u < NT) ? u : (NT - 1);
    int sg = uc >> 4;
    const __bf16* p = (sg == 0) ? s.b0 : ((sg == 1) ? s.b1 : s.b2);
    gld16(p + ((size_t)(q << 6)) * DD + ((uc & 15) << 6) + rk, dst + (q << 13) + wvoff);
  };
  auto rdA = [&](char* l, int m, int cx) {
    return *(const bf16x8*)(l + rbA + (m << 11) + cx);
  };
  auto rdB = [&](char* l, int n, int cx) {
    return *(const bf16x8*)(l + rbB + (n << 11) + cx);
  };

  // ---- prologue: tile0 fully, tile1 A-quarters 0,2 ----
#pragma unroll
  for (int q = 0; q < 4; ++q) stA(0, q, LA0);
#pragma unroll
  for (int q = 0; q < 4; ++q) stB(0, q, LB0);
  stA(1, 0, LA1); stA(1, 2, LA1);
  asm volatile("s_waitcnt vmcnt(2)" ::: "memory");
  __builtin_amdgcn_s_barrier();

  auto tile = [&](char* lA, char* lB, char* lA1, char* lB1, int t) {
    bf16x8 a0[4][2], a1[4][2], b0[2][2], b1[2][2];
    // ---- phase 0: msub0 x nsub0 ----
#pragma unroll
    for (int m = 0; m < 4; ++m) { a0[m][0] = rdA(lA, m, cx0); a0[m][1] = rdA(lA, m, cx1); }
#pragma unroll
    for (int n = 0; n < 2; ++n) { b0[n][0] = rdB(lB, n, cx0); b0[n][1] = rdB(lB, n, cx1); }
    stA(t + 1, 1, lA1); stA(t + 1, 3, lA1);
    __builtin_amdgcn_s_barrier();
    asm volatile("s_waitcnt lgkmcnt(0)" ::: "memory");
    __builtin_amdgcn_s_setprio(1);
#pragma unroll
    for (int m = 0; m < 4; ++m)
#pragma unroll
      for (int n = 0; n < 2; ++n) {
        acc[m][n] = mfma16x16x32(a0[m][0], b0[n][0], acc[m][n]);
        acc[m][n] = mfma16x16x32(a0[m][1], b0[n][1], acc[m][n]);
      }
    __builtin_amdgcn_s_setprio(0);
    __builtin_amdgcn_s_barrier();
    // ---- phase 1: msub0 x nsub1 ----
#pragma unroll
    for (int n = 0; n < 2; ++n) { b1[n][0] = rdB(lB, n + 2, cx0); b1[n][1] = rdB(lB, n + 2, cx1); }
    stB(t + 1, 0, lB1); stB(t + 1, 1, lB1);
    __builtin_amdgcn_s_barrier();
    asm volatile("s_waitcnt lgkmcnt(0)" ::: "memory");
    __builtin_amdgcn_s_setprio(1);
#pragma unroll
    for (int m = 0; m < 4; ++m)
#pragma unroll
      for (int n = 0; n < 2; ++n) {
        acc[m][n + 2] = mfma16x16x32(a0[m][0], b1[n][0], acc[m][n + 2]);
        acc[m][n + 2] = mfma16x16x32(a0[m][1], b1[n][1], acc[m][n + 2]);
      }
    __builtin_amdgcn_s_setprio(0);
    __builtin_amdgcn_s_barrier();
    // ---- phase 2: msub1 x nsub0 ----
#pragma unroll
    for (int m = 0; m < 4; ++m) { a1[m][0] = rdA(lA, m + 4, cx0); a1[m][1] = rdA(lA, m + 4, cx1); }
    stB(t + 1, 2, lB1); stB(t + 1, 3, lB1);
    __builtin_amdgcn_s_barrier();
    asm volatile("s_waitcnt lgkmcnt(0)" ::: "memory");
    __builtin_amdgcn_s_setprio(1);
#pragma unroll
    for (int m = 0; m < 4; ++m)
#pragma unroll
      for (int n = 0; n < 2; ++n) {
        acc[m + 4][n] = mfma16x16x32(a1[m][0], b0[n][0], acc[m + 4][n]);
        acc[m + 4][n] = mfma16x16x32(a1[m][1], b0[n][1], acc[m + 4][n]);
      }
    __builtin_amdgcn_s_setprio(0);
    __builtin_amdgcn_s_barrier();
    // ---- phase 3: msub1 x nsub1 ----
    stA(t + 2, 0, lA); stA(t + 2, 2, lA);
    __builtin_amdgcn_s_barrier();
    asm volatile("s_waitcnt lgkmcnt(0)" ::: "memory");
    __builtin_amdgcn_s_setprio(1);
#pragma unroll
    for (int m = 0; m < 4; ++m)
#pragma unroll
      for (int n = 0; n < 2; ++n) {
        acc[m + 4][n + 2] = mfma16x16x32(a1[m][0], b1[n][0], acc[m + 4][n + 2]);
        acc[m + 4][n + 2] = mfma16x16x32(a1[m][1], b1[n][1], acc[m + 4][n + 2]);
      }
    __builtin_amdgcn_s_setprio(0);
    asm volatile("s_waitcnt vmcnt(2)" ::: "memory"); // next tile fully staged; keeps 2 newest in flight
    __builtin_amdgcn_s_barrier();
  };

  for (int t = 0; t < NT; t += 2) {
    tile(LA0, LB0, LA1, LB1, t);
    tile(LA1, LB1, LA0, LB0, t + 1);
  }
  asm volatile("s_waitcnt vmcnt(0)" ::: "memory"); // drain tail clamp stages before endpgm
}

// ---------------- scores = [Qh|Qh|Ql] . [Kh|Kl|Kh]^T, fp32 out ----------------
__global__ __launch_bounds__(512, 2)
void gemm256_scores(const __bf16* __restrict__ Qh, const __bf16* __restrict__ Ql,
                    const __bf16* __restrict__ Kh, const __bf16* __restrict__ Kl,
                    float* __restrict__ Sf) {
  extern __shared__ char smem[];
  const int z = blockIdx.z;
  const size_t zo = (size_t)z * SS * DD;
  const int row0 = blockIdx.y * 256, col0 = blockIdx.x * 256;
  const size_t ra = zo + (size_t)row0 * DD, rb = zo + (size_t)col0 * DD;
  Segs s{Qh + ra, Qh + ra, Ql + ra, Kh + rb, Kl + rb, Kh + rb};
  f32x4 acc[8][4] = {};
  gemm256_core(s, 48, smem, acc);

  float* C = Sf + (size_t)z * SS * SS;
  const int lane = threadIdx.x & 63, wave = threadIdx.x >> 6;
  const int wm = wave >> 2, wn = wave & 3;
#pragma unroll
  for (int m = 0; m < 8; ++m)
#pragma unroll
    for (int n = 0; n < 4; ++n) {
      int col = col0 + wn * 64 + n * 16 + (lane & 15);
      int rowb = row0 + wm * 128 + m * 16 + (lane >> 4) * 4;
#pragma unroll
      for (int j = 0; j < 4; ++j)
        C[(size_t)(rowb + j) * SS + col] = acc[m][n][j];
    }
}

// ---------------- fused Q/K/V projections (z = 0/1/2) ----------------
struct ProjPtrs {
  const __bf16 *xh, *xl;
  const __bf16 *wqh, *wql, *wkh, *wkl, *wvh;
  const float *bq, *bk, *bv;
  __bf16 *Qh, *Ql, *Kh, *Kl, *Vb;
};

__global__ __launch_bounds__(512, 2)
void gemm256_proj(ProjPtrs P) {
  extern __shared__ char smem[];
  const int z = blockIdx.z;
  const int row0 = blockIdx.y * 256, col0 = blockIdx.x * 256;

  const __bf16 *B0, *B1, *B2;
  const float* bias;
  __bf16 *CH, *CL;
  int NT;
  if (z == 0)      { B0 = P.wqh; B1 = P.wql; B2 = P.wqh; bias = P.bq; CH = P.Qh; CL = P.Ql; NT = 48; }
  else if (z == 1) { B0 = P.wkh; B1 = P.wkl; B2 = P.wkh; bias = P.bk; CH = P.Kh; CL = P.Kl; NT = 48; }
  else             { B0 = P.wvh; B1 = P.wvh; B2 = P.wvh; bias = P.bv; CH = P.Vb; CL = nullptr; NT = 16; }

  const size_t ra = (size_t)row0 * DD, rb = (size_t)col0 * DD;
  Segs s{P.xh + ra, P.xh + ra, P.xl + ra, B0 + rb, B1 + rb, B2 + rb};
  f32x4 acc[8][4] = {};
  gemm256_core(s, NT, smem, acc);

  const int lane = threadIdx.x & 63, wave = threadIdx.x >> 6;
  const int wm = wave >> 2, wn = wave & 3;
#pragma unroll
  for (int m = 0; m < 8; ++m)
#pragma unroll
    for (int n = 0; n < 4; ++n) {
      int col = col0 + wn * 64 + n * 16 + (lane & 15);
      float bv = bias[col];
      int rowb = row0 + wm * 128 + m * 16 + (lane >> 4) * 4;
#pragma unroll
      for (int j = 0; j < 4; ++j) {
        float v = acc[m][n][j] + bv;
        size_t idx = (size_t)(rowb + j) * DD + col;
        if (z < 2) {
          __bf16 h = (__bf16)v;
          CH[idx] = h;
          CL[idx] = (__bf16)(v - (float)h);
        } else {
          CH[idx] = (__bf16)v;
        }
      }
    }
}

// ---------------- split fp32 -> bf16 hi/lo ----------------
__global__ __launch_bounds__(256)
void split_f32_bf16x2(const float* __restrict__ in, __bf16* __restrict__ hi,
                      __bf16* __restrict__ lo, int n) {
  int stride = gridDim.x * blockDim.x;
  for (int i = blockIdx.x * blockDim.x + threadIdx.x; i * 4 < n; i += stride) {
    f32x4 x = *(const f32x4*)(in + (size_t)i * 4);
    bf16x4 h, l;
#pragma unroll
    for (int e = 0; e < 4; ++e) {
      __bf16 hh = (__bf16)x[e];
      h[e] = hh;
      l[e] = (__bf16)(x[e] - (float)hh);
    }
    *(bf16x4*)(hi + (size_t)i * 4) = h;
    *(bf16x4*)(lo + (size_t)i * 4) = l;
  }
}

// ---------------- legacy 128^2 GEMM (kept for PV) ----------------
DEVFN void stage_tile(__bf16* ldsb, const __bf16* gptr, int ld, int tid) {
  char* lb = (char*)ldsb + ((tid >> 6) << 10);
  gld16(gptr, lb);
  gld16(gptr + (size_t)64 * ld, lb + 4096);
}

__global__ __launch_bounds__(256)
void gemm_bt_pv(const __bf16* __restrict__ Ah, const __bf16* __restrict__ Bh,
                float* __restrict__ Cf, int M, int N, int K,
                size_t sAb, size_t sBb, size_t sCb) {
  const int b = blockIdx.z;
  Ah += (size_t)b * sAb; Bh += (size_t)b * sBb;

  __shared__ __bf16 lds[2][128 * 32];

  const int tid = threadIdx.x;
  const int lane = tid & 63, wave = tid >> 6;
  const int wm = (wave >> 1) * 64, wn = (wave & 1) * 64;
  const int row0 = blockIdx.y * 128, col0 = blockIdx.x * 128;
  const int sr = tid >> 2, sc = (tid & 3) * 8;

  const __bf16* gA = Ah + (size_t)(row0 + sr) * K + sc;
  const __bf16* gB = Bh + (size_t)(col0 + sr) * K + sc;

  f32x4 acc[4][4] = {};

  for (int k0 = 0; k0 < K; k0 += 32) {
    __syncthreads();
    stage_tile(lds[0], gA + k0, K, tid);
    stage_tile(lds[1], gB + k0, K, tid);
    __syncthreads();

    const int kg = (lane >> 4) * 8;
    bf16x8 ah[4], bh[4];
#pragma unroll
    for (int m = 0; m < 4; ++m)
      ah[m] = *(const bf16x8*)&lds[0][(wm + m * 16 + (lane & 15)) * 32 + kg];
#pragma unroll
    for (int n = 0; n < 4; ++n)
      bh[n] = *(const bf16x8*)&lds[1][(wn + n * 16 + (lane & 15)) * 32 + kg];
#pragma unroll
    for (int m = 0; m < 4; ++m)
#pragma unroll
      for (int n = 0; n < 4; ++n)
        acc[m][n] = mfma16x16x32(ah[m], bh[n], acc[m][n]);
  }

  Cf += (size_t)b * sCb;
#pragma unroll
  for (int m = 0; m < 4; ++m)
#pragma unroll
    for (int n = 0; n < 4; ++n) {
      int gcol = col0 + wn + n * 16 + (lane & 15);
#pragma unroll
      for (int j = 0; j < 4; ++j) {
        int grow = row0 + wm + m * 16 + (lane >> 4) * 4 + j;
        Cf[(size_t)grow * N + gcol] = acc[m][n][j];
      }
    }
}

// ---------------- transpose bf16 ----------------
__global__ __launch_bounds__(256)
void transpose_bf16(const __bf16* __restrict__ in, __bf16* __restrict__ out,
                    int rows, int cols) {
  __shared__ __bf16 t[32][33];
  const int b = blockIdx.z;
  in  += (size_t)b * rows * cols;
  out += (size_t)b * rows * cols;
  const int i0 = blockIdx.y * 32, j0 = blockIdx.x * 32;
  const int tx = threadIdx.x & 31, ty0 = threadIdx.x >> 5;
#pragma unroll
  for (int p = 0; p < 4; ++p) {
    int ty = ty0 + p * 8;
    t[ty][tx] = in[(size_t)(i0 + ty) * cols + (j0 + tx)];
  }
  __syncthreads();
#pragma unroll
  for (int p = 0; p < 4; ++p) {
    int ty = ty0 + p * 8;
    out[(size_t)(j0 + ty) * rows + (i0 + tx)] = t[tx][ty];
  }
}

// ---------------- softmax + dropout ----------------
__global__ __launch_bounds__(256)
void softmax_dropout(const float* __restrict__ Sf, const float* __restrict__ U,
                     __bf16* __restrict__ P) {
  __shared__ float red[4];
  const size_t row = blockIdx.x;
  const float* s = Sf + row * SS;
  const float* u = U + row * SS;
  __bf16* p = P + row * SS;
  const int tid = threadIdx.x, lane = tid & 63, wave = tid >> 6;

  f32x4 v[4];
  float m = -3.0e38f;
#pragma unroll
  for (int j = 0; j < 4; ++j) {
    v[j] = *(const f32x4*)(s + (size_t)(j * 256 + tid) * 4);
#pragma unroll
    for (int e = 0; e < 4; ++e) m = fmaxf(m, v[j][e]);
  }
#pragma unroll
  for (int o = 32; o > 0; o >>= 1) m = fmaxf(m, __shfl_xor(m, o));
  if (lane == 0) red[wave] = m;
  __syncthreads();
  m = fmaxf(fmaxf(red[0], red[1]), fmaxf(red[2], red[3]));

  float sum = 0.0f;
#pragma unroll
  for (int j = 0; j < 4; ++j)
#pragma unroll
    for (int e = 0; e < 4; ++e) { float ex = __expf(v[j][e] - m); v[j][e] = ex; sum += ex; }
#pragma unroll
  for (int o = 32; o > 0; o >>= 1) sum += __shfl_xor(sum, o);
  __syncthreads();
  if (lane == 0) red[wave] = sum;
  __syncthreads();
  sum = red[0] + red[1] + red[2] + red[3];
  const float scale = 1.25f / sum;

#pragma unroll
  for (int j = 0; j < 4; ++j) {
    f32x4 uu = *(const f32x4*)(u + (size_t)(j * 256 + tid) * 4);
    bf16x4 out;
#pragma unroll
    for (int e = 0; e < 4; ++e)
      out[e] = (__bf16)((uu[e] >= 0.2f) ? v[j][e] * scale : 0.0f);
    *(bf16x4*)(p + (size_t)(j * 256 + tid) * 4) = out;
  }
}

// ---------------- launcher ----------------
extern "C" void kernel_launch(void* const* d_in, const int* in_sizes, int n_in,
                              void* d_out, int out_size, void* d_ws, size_t ws_size,
                              hipStream_t stream) {
  if (ws_size < WS_NEEDED) return;

  const float* x  = (const float*)d_in[0];
  const float* Wq = (const float*)d_in[1];
  const float* bq = (const float*)d_in[2];
  const float* Wk = (const float*)d_in[3];
  const float* bk = (const float*)d_in[4];
  const float* Wv = (const float*)d_in[5];
  const float* bv = (const float*)d_in[6];
  const float* du = (const float*)d_in[7];

  char* ws = (char*)d_ws;
  __bf16* Vt  = (__bf16*)(ws + O_VT);
  __bf16* Pb  = (__bf16*)(ws + O_ATTN);
  __bf16* Qh  = (__bf16*)(ws + O_QH);
  __bf16* Ql  = (__bf16*)(ws + O_QL);
  __bf16* Kh  = (__bf16*)(ws + O_KH);
  __bf16* Kl  = (__bf16*)(ws + O_KL);
  float*  Sf  = (float*) (ws + O_S);
  __bf16* xh  = (__bf16*)(ws + O_XH);
  __bf16* xl  = (__bf16*)(ws + O_XL);
  __bf16* wqh = (__bf16*)(ws + O_WQH);
  __bf16* wql = (__bf16*)(ws + O_WQL);
  __bf16* wkh = (__bf16*)(ws + O_WKH);
  __bf16* wkl = (__bf16*)(ws + O_WKL);
  __bf16* wvh = (__bf16*)(ws + O_WVH);
  __bf16* wvl = (__bf16*)(ws + O_WVL);
  float*  out = (float*)d_out;

  hipFuncSetAttribute((const void*)gemm256_scores,
                      hipFuncAttributeMaxDynamicSharedMemorySize, 131072);
  hipFuncSetAttribute((const void*)gemm256_proj,
                      hipFuncAttributeMaxDynamicSharedMemorySize, 131072);

  // 1) splits
  split_f32_bf16x2<<<2048, 256, 0, stream>>>(x,  xh,  xl,  MROWS * DD);
  split_f32_bf16x2<<<256,  256, 0, stream>>>(Wq, wqh, wql, DD * DD);
  split_f32_bf16x2<<<256,  256, 0, stream>>>(Wk, wkh, wkl, DD * DD);
  split_f32_bf16x2<<<256,  256, 0, stream>>>(Wv, wvh, wvl, DD * DD);

  // 2) fused Q/K/V projections (one dispatch, 384 blocks)
  ProjPtrs P{xh, xl, wqh, wql, wkh, wkl, wvh, bq, bk, bv, Qh, Ql, Kh, Kl, Pb /*Vb alias placeholder*/};
  // V output goes to the O_V region used by the transpose below:
  P.Vb = (__bf16*)(ws + O_V);
  gemm256_proj<<<dim3(DD / 256, MROWS / 256, 3), 512, 131072, stream>>>(P);

  // 3) V transpose -> Vt [2][1024][4096]
  transpose_bf16<<<dim3(DD / 32, SS / 32, BB), 256, 0, stream>>>((__bf16*)(ws + O_V), Vt, SS, DD);

  // 4) scores = Q K^T (split via K-concat, fp32 out)
  gemm256_scores<<<dim3(SS / 256, SS / 256, BB), 512, 131072, stream>>>(Qh, Ql, Kh, Kl, Sf);

  // 5) softmax + dropout -> attn bf16 (overwrites dead Q/K splits)
  softmax_dropout<<<MROWS, 256, 0, stream>>>(Sf, du, Pb);

  // 6) out = attn @ V^T-layout
  gemm_bt_pv<<<dim3(DD / 128, SS / 128, BB), 256, 0, stream>>>(
      Pb, Vt, out, SS, DD, SS,
      (size_t)SS * SS, (size_t)DD * SS, (size_t)SS * DD);
}